// Round 2
// baseline (586.314 us; speedup 1.0000x reference)
//
#include <hip/hip_runtime.h>
#include <hip/hip_bf16.h>
#include <math.h>

// Problem constants (B=4,S=1024,D=1024,H=4096,E=8,K=2)
#define TOKENS 4096
#define DD 1024
#define HH 4096
#define NE 8
#define PAIRS 8192     // TOKENS * K
#define ROWCAP 8448    // PAIRS + 256 slack for tile overread (BM=256)
#define TILE_CAP 40    // max sum ceil(n_e/256) = 32 + 7

typedef __bf16 bf16x8 __attribute__((ext_vector_type(8)));
typedef float f32x4 __attribute__((ext_vector_type(4)));

__device__ __forceinline__ unsigned short f2bf(float f) {
  union { float f; unsigned int u; } c; c.f = f;
  unsigned int x = c.u;
  return (unsigned short)((x + 0x7fffu + ((x >> 16) & 1u)) >> 16);  // RNE
}

__device__ __forceinline__ void lds16(void* l, const void* g) {
  __builtin_amdgcn_global_load_lds((const __attribute__((address_space(1))) void*)g,
                                   (__attribute__((address_space(3))) void*)l, 16, 0, 0);
}

// ---------------- init: zero expert counts ----------------
__global__ void init_kernel(int* counts) {
  if (threadIdx.x < NE) counts[threadIdx.x] = 0;
}

// ---------------- transpose+convert: [E][R][C] f32 -> [E][C][R] bf16 ----------------
__global__ __launch_bounds__(256) void transpose_kernel(const float* __restrict__ in,
                                                        unsigned short* __restrict__ out,
                                                        int R, int C) {
  int ntr = R >> 6, ntc = C >> 6;
  int per_e = ntr * ntc;
  int b = blockIdx.x;
  int e = b / per_e;
  int rem = b - e * per_e;
  int tr = rem / ntc, tc = rem - (rem / ntc) * ntc;
  const float* ie = in + (size_t)e * R * C;
  unsigned short* oe = out + (size_t)e * R * C;

  __shared__ float t[64][68];
  int tid = threadIdx.x;
  int lr = tid >> 2;
  int c4 = (tid & 3) << 4;
  const float* src = ie + (size_t)(tr * 64 + lr) * C + tc * 64 + c4;
  float4 v0 = *(const float4*)(src);
  float4 v1 = *(const float4*)(src + 4);
  float4 v2 = *(const float4*)(src + 8);
  float4 v3 = *(const float4*)(src + 12);
  *(float4*)&t[lr][c4] = v0;
  *(float4*)&t[lr][c4 + 4] = v1;
  *(float4*)&t[lr][c4 + 8] = v2;
  *(float4*)&t[lr][c4 + 12] = v3;
  __syncthreads();

  int oc = tid >> 2;            // local out-row (= input col)
  int r0 = (tid & 3) << 4;      // 16 input rows per thread
  unsigned int pk[8];
#pragma unroll
  for (int i = 0; i < 8; i++) {
    unsigned int lo = f2bf(t[r0 + 2 * i][oc]);
    unsigned int hi = f2bf(t[r0 + 2 * i + 1][oc]);
    pk[i] = lo | (hi << 16);
  }
  unsigned short* dst = oe + (size_t)(tc * 64 + oc) * R + tr * 64 + r0;
  *(uint4*)(dst) = make_uint4(pk[0], pk[1], pk[2], pk[3]);
  *(uint4*)(dst + 8) = make_uint4(pk[4], pk[5], pk[6], pk[7]);
}

// ---------------- gate: logits -> top2 -> renorm weights -> atomic routing ----------------
__global__ __launch_bounds__(256) void gate_kernel(const float* __restrict__ x,
    const float* __restrict__ Wg, const float* __restrict__ bg,
    int* __restrict__ counts, int* __restrict__ tok_e, int* __restrict__ tok_slot,
    float* __restrict__ tok_w) {
  int t = blockIdx.x, tid = threadIdx.x;
  const float* xr = x + (size_t)t * DD;
  float p[8] = {0, 0, 0, 0, 0, 0, 0, 0};
  for (int d = tid; d < DD; d += 256) {
    float xv = xr[d];
    const float4* wrow = (const float4*)(Wg + (size_t)d * NE);
    float4 w0 = wrow[0], w1 = wrow[1];
    p[0] += xv * w0.x; p[1] += xv * w0.y; p[2] += xv * w0.z; p[3] += xv * w0.w;
    p[4] += xv * w1.x; p[5] += xv * w1.y; p[6] += xv * w1.z; p[7] += xv * w1.w;
  }
#pragma unroll
  for (int e = 0; e < 8; e++) {
    p[e] += __shfl_down(p[e], 32);
    p[e] += __shfl_down(p[e], 16);
    p[e] += __shfl_down(p[e], 8);
    p[e] += __shfl_down(p[e], 4);
    p[e] += __shfl_down(p[e], 2);
    p[e] += __shfl_down(p[e], 1);
  }
  __shared__ float red[4][8];
  if ((tid & 63) == 0) {
#pragma unroll
    for (int e = 0; e < 8; e++) red[tid >> 6][e] = p[e];
  }
  __syncthreads();
  if (tid == 0) {
    float l[8];
#pragma unroll
    for (int e = 0; e < 8; e++) l[e] = red[0][e] + red[1][e] + red[2][e] + red[3][e] + bg[e];
    int e0 = 0; float l0 = l[0];
    for (int e = 1; e < 8; e++) if (l[e] > l0) { e0 = e; l0 = l[e]; }
    int e1 = -1; float l1 = -3.4e38f;
    for (int e = 0; e < 8; e++) if (e != e0 && l[e] > l1) { e1 = e; l1 = l[e]; }
    // softmax+top2+renorm == logistic on top-2 logit gap
    float w0 = 1.f / (1.f + __expf(l1 - l0));
    float w1 = 1.f - w0;
    int s0 = atomicAdd(&counts[e0], 1);
    int s1 = atomicAdd(&counts[e1], 1);
    tok_e[2 * t] = e0;     tok_slot[2 * t] = s0;     tok_w[2 * t] = w0;
    tok_e[2 * t + 1] = e1; tok_slot[2 * t + 1] = s1; tok_w[2 * t + 1] = w1;
  }
}

// ---------------- scan: expert offsets + tile map (BM=256) ----------------
__global__ void scan_kernel(const int* __restrict__ counts, int* __restrict__ offsets,
                            int* __restrict__ tm_e, int* __restrict__ tm_row0,
                            int* __restrict__ tm_nrow, int* __restrict__ ntp) {
  if (threadIdx.x != 0 || blockIdx.x != 0) return;
  int c[NE];
#pragma unroll
  for (int e = 0; e < NE; e++) c[e] = counts[e];
  int off = 0, nt = 0;
  for (int e = 0; e < NE; e++) {
    offsets[e] = off;
    for (int r = 0; r < c[e]; r += 256) {
      tm_e[nt] = e;
      tm_row0[nt] = off + r;
      tm_nrow[nt] = (c[e] - r < 256) ? (c[e] - r) : 256;
      nt++;
    }
    off += c[e];
  }
  *ntp = nt;
}

// ---------------- gather: x rows -> per-expert compact bf16 A matrix ----------------
__global__ __launch_bounds__(64) void gather_kernel(const float* __restrict__ x,
    const int* __restrict__ tok_e, const int* __restrict__ tok_slot,
    const float* __restrict__ tok_w, const int* __restrict__ offsets,
    unsigned short* __restrict__ Xe, int* __restrict__ pair_row, float* __restrict__ rw) {
  int pp = blockIdx.x, tid = threadIdx.x;
  int e = tok_e[pp];
  int row = offsets[e] + tok_slot[pp];
  int t = pp >> 1;
  const float* src = x + (size_t)t * DD + tid * 16;
  float4 v0 = *(const float4*)(src);
  float4 v1 = *(const float4*)(src + 4);
  float4 v2 = *(const float4*)(src + 8);
  float4 v3 = *(const float4*)(src + 12);
  unsigned int pk[8];
  pk[0] = f2bf(v0.x) | ((unsigned int)f2bf(v0.y) << 16);
  pk[1] = f2bf(v0.z) | ((unsigned int)f2bf(v0.w) << 16);
  pk[2] = f2bf(v1.x) | ((unsigned int)f2bf(v1.y) << 16);
  pk[3] = f2bf(v1.z) | ((unsigned int)f2bf(v1.w) << 16);
  pk[4] = f2bf(v2.x) | ((unsigned int)f2bf(v2.y) << 16);
  pk[5] = f2bf(v2.z) | ((unsigned int)f2bf(v2.w) << 16);
  pk[6] = f2bf(v3.x) | ((unsigned int)f2bf(v3.y) << 16);
  pk[7] = f2bf(v3.z) | ((unsigned int)f2bf(v3.w) << 16);
  unsigned short* dst = Xe + (size_t)row * DD + tid * 16;
  *(uint4*)(dst) = make_uint4(pk[0], pk[1], pk[2], pk[3]);
  *(uint4*)(dst + 8) = make_uint4(pk[4], pk[5], pk[6], pk[7]);
  if (tid == 0) { pair_row[pp] = row; rw[row] = tok_w[pp]; }
}

// ---------------- GEMM1: h = silu(Xe*WaT^T + ba) * (Xe*W1T^T + b1), bf16 out ----------------
// BM=256, BN=128 (dual-B), BK=32, 512 threads (8 waves, 2M x 4N), per-wave 128x32 per proj.
// Double-buffered LDS (64KB), depth-1 prefetch, counted vmcnt(4) BEFORE barrier.
__global__ __launch_bounds__(512, 2) void gemm1_kernel(
    const unsigned short* __restrict__ Xe,
    const unsigned short* __restrict__ WaT,   // [E][H][D] bf16
    const unsigned short* __restrict__ W1T,
    const float* __restrict__ ba, const float* __restrict__ b1,
    unsigned short* __restrict__ h,
    const int* __restrict__ tm_e, const int* __restrict__ tm_row0,
    const int* __restrict__ tm_nrow, const int* __restrict__ ntp) {
  extern __shared__ unsigned short sm[];   // 2 bufs x (A 8192 | Ba 4096 | Bu 4096) shorts
  // T1 bijective XCD swizzle (gridDim % 8 == 0): same-tile n-blocks co-XCD
  int chunk = gridDim.x >> 3;
  int work = (blockIdx.x & 7) * chunk + (blockIdx.x >> 3);
  int tile = work >> 5;
  if (tile >= *ntp) return;
  int n0 = (work & 31) << 7;
  int e = tm_e[tile], row0 = tm_row0[tile], nrow = tm_nrow[tile];

  int tid = threadIdx.x;
  int lane = tid & 63, wid = tid >> 6;
  int wm = wid >> 2, wn = wid & 3;          // 2M x 4N waves
  int fr = lane & 15, kc = lane >> 4;

  const unsigned short* gA = Xe + (size_t)row0 * DD;
  const unsigned short* gBa = WaT + ((size_t)e << 22) + (size_t)n0 * DD;
  const unsigned short* gBu = W1T + ((size_t)e << 22) + (size_t)n0 * DD;

  int sr = tid >> 2;                 // staging row 0..127
  int sk = (tid & 3) << 3;           // k offset (shorts)

  f32x4 accA[8][2], accU[8][2];
  f32x4 z = {0.f, 0.f, 0.f, 0.f};
#pragma unroll
  for (int m = 0; m < 8; m++)
#pragma unroll
    for (int n = 0; n < 2; n++) { accA[m][n] = z; accU[m][n] = z; }

  // stage K-tile kt into buffer buf (4 gload_lds per thread)
  auto stage = [&](int kt, int buf) {
    int k0 = kt << 5;
    unsigned short* L = sm + buf * 16384;
    lds16(L + (size_t)tid * 8,         gA + (size_t)sr * DD + k0 + sk);
    lds16(L + (size_t)(tid + 512) * 8, gA + (size_t)(sr + 128) * DD + k0 + sk);
    lds16(L + 8192 + (size_t)tid * 8,  gBa + (size_t)sr * DD + k0 + sk);
    lds16(L + 12288 + (size_t)tid * 8, gBu + (size_t)sr * DD + k0 + sk);
  };

  stage(0, 0);
  for (int t = 0; t < 32; ++t) {
    int nxt = (t + 1 < 32) ? t + 1 : 31;       // redundant re-stage at tail keeps vmcnt uniform
    stage(nxt, (t + 1) & 1);
    // counted wait BEFORE barrier: all threads' stage(t) certified after barrier
    asm volatile("s_waitcnt vmcnt(4)\ns_barrier" ::: "memory");
    const unsigned short* L = sm + (t & 1) * 16384;
    bf16x8 a[8], bA[2], bU[2];
#pragma unroll
    for (int m = 0; m < 8; m++)
      a[m] = *(const bf16x8*)(L + (wm * 128 + m * 16 + fr) * 32 + kc * 8);
#pragma unroll
    for (int n = 0; n < 2; n++) {
      bA[n] = *(const bf16x8*)(L + 8192 + (wn * 32 + n * 16 + fr) * 32 + kc * 8);
      bU[n] = *(const bf16x8*)(L + 12288 + (wn * 32 + n * 16 + fr) * 32 + kc * 8);
    }
#pragma unroll
    for (int m = 0; m < 8; m++)
#pragma unroll
      for (int n = 0; n < 2; n++) {
        accA[m][n] = __builtin_amdgcn_mfma_f32_16x16x32_bf16(a[m], bA[n], accA[m][n], 0, 0, 0);
        accU[m][n] = __builtin_amdgcn_mfma_f32_16x16x32_bf16(a[m], bU[n], accU[m][n], 0, 0, 0);
      }
    // reads retired before barrier so next iter's stage can't clobber in-flight ds_reads
    asm volatile("s_waitcnt lgkmcnt(0)\ns_barrier" ::: "memory");
  }

  // epilogue: SwiGLU, store bf16 h
  int lr4 = kc * 4;
#pragma unroll
  for (int n = 0; n < 2; n++) {
    int col = n0 + wn * 32 + n * 16 + fr;
    float bav = ba[e * HH + col];
    float buv = b1[e * HH + col];
#pragma unroll
    for (int m = 0; m < 8; m++) {
#pragma unroll
      for (int j = 0; j < 4; j++) {
        int r = wm * 128 + m * 16 + lr4 + j;
        if (r < nrow) {
          float av = accA[m][n][j] + bav;
          float uv = accU[m][n][j] + buv;
          float s = __builtin_amdgcn_rcpf(1.f + __expf(-av));
          float hv = av * s * uv;
          h[(size_t)(row0 + r) * HH + col] = f2bf(hv);
        }
      }
    }
  }
}

// ---------------- GEMM2: contrib = w * (h*W2T^T + b2), f32 out ----------------
// BM=256, BN=128, BK=32, 512 threads (8 waves, 4M x 2N), per-wave 64x64.
// Double-buffered LDS (48KB), depth-1 prefetch, counted vmcnt(3).
__global__ __launch_bounds__(512, 2) void gemm2_kernel(
    const unsigned short* __restrict__ h,
    const unsigned short* __restrict__ W2T,   // [E][D][H] bf16
    const float* __restrict__ b2, const float* __restrict__ rw,
    float* __restrict__ contrib,
    const int* __restrict__ tm_e, const int* __restrict__ tm_row0,
    const int* __restrict__ tm_nrow, const int* __restrict__ ntp) {
  extern __shared__ unsigned short sm[];   // 2 bufs x (A 8192 | B 4096) shorts
  int chunk = gridDim.x >> 3;
  int work = (blockIdx.x & 7) * chunk + (blockIdx.x >> 3);
  int tile = work >> 3;
  if (tile >= *ntp) return;
  int n0 = (work & 7) << 7;
  int e = tm_e[tile], row0 = tm_row0[tile], nrow = tm_nrow[tile];

  int tid = threadIdx.x;
  int lane = tid & 63, wid = tid >> 6;
  int wm = wid >> 1, wn = wid & 1;          // 4M x 2N waves
  int fr = lane & 15, kc = lane >> 4;

  const unsigned short* gA = h + (size_t)row0 * HH;
  const unsigned short* gB = W2T + ((size_t)e << 22) + (size_t)n0 * HH;

  int sr = tid >> 2;
  int sk = (tid & 3) << 3;

  f32x4 acc[4][4];
  f32x4 z = {0.f, 0.f, 0.f, 0.f};
#pragma unroll
  for (int m = 0; m < 4; m++)
#pragma unroll
    for (int n = 0; n < 4; n++) acc[m][n] = z;

  auto stage = [&](int kt, int buf) {
    int k0 = kt << 5;
    unsigned short* L = sm + buf * 12288;
    lds16(L + (size_t)tid * 8,         gA + (size_t)sr * HH + k0 + sk);
    lds16(L + (size_t)(tid + 512) * 8, gA + (size_t)(sr + 128) * HH + k0 + sk);
    lds16(L + 8192 + (size_t)tid * 8,  gB + (size_t)sr * HH + k0 + sk);
  };

  stage(0, 0);
  for (int t = 0; t < 128; ++t) {
    int nxt = (t + 1 < 128) ? t + 1 : 127;
    stage(nxt, (t + 1) & 1);
    asm volatile("s_waitcnt vmcnt(3)\ns_barrier" ::: "memory");
    const unsigned short* L = sm + (t & 1) * 12288;
    bf16x8 a[4], b[4];
#pragma unroll
    for (int m = 0; m < 4; m++)
      a[m] = *(const bf16x8*)(L + (wm * 64 + m * 16 + fr) * 32 + kc * 8);
#pragma unroll
    for (int n = 0; n < 4; n++)
      b[n] = *(const bf16x8*)(L + 8192 + (wn * 64 + n * 16 + fr) * 32 + kc * 8);
#pragma unroll
    for (int m = 0; m < 4; m++)
#pragma unroll
      for (int n = 0; n < 4; n++)
        acc[m][n] = __builtin_amdgcn_mfma_f32_16x16x32_bf16(a[m], b[n], acc[m][n], 0, 0, 0);
    asm volatile("s_waitcnt lgkmcnt(0)\ns_barrier" ::: "memory");
  }

  float b2v[4];
#pragma unroll
  for (int n = 0; n < 4; n++) b2v[n] = b2[e * DD + n0 + wn * 64 + n * 16 + fr];
  int lr4 = kc * 4;
#pragma unroll
  for (int m = 0; m < 4; m++) {
#pragma unroll
    for (int j = 0; j < 4; j++) {
      int r = wm * 64 + m * 16 + lr4 + j;
      if (r < nrow) {
        float wv = rw[row0 + r];
        float* dst = contrib + (size_t)(row0 + r) * DD + n0 + wn * 64 + fr;
#pragma unroll
        for (int n = 0; n < 4; n++)
          dst[n * 16] = wv * (acc[m][n][j] + b2v[n]);
      }
    }
  }
}

// ---------------- combine: out[t] = contrib[row(t,0)] + contrib[row(t,1)] ----------------
__global__ __launch_bounds__(256) void combine_kernel(const float* __restrict__ contrib,
    const int* __restrict__ pair_row, float* __restrict__ out) {
  int t = blockIdx.x, tid = threadIdx.x;
  int r0 = pair_row[2 * t], r1 = pair_row[2 * t + 1];
  const float4* c0 = (const float4*)(contrib + (size_t)r0 * DD);
  const float4* c1 = (const float4*)(contrib + (size_t)r1 * DD);
  float4* o = (float4*)(out + (size_t)t * DD);
  float4 a = c0[tid], b = c1[tid];
  o[tid] = make_float4(a.x + b.x, a.y + b.y, a.z + b.z, a.w + b.w);
}

extern "C" void kernel_launch(void* const* d_in, const int* in_sizes, int n_in,
                              void* d_out, int out_size, void* d_ws, size_t ws_size,
                              hipStream_t stream) {
  const float* x  = (const float*)d_in[0];
  const float* Wg = (const float*)d_in[1];
  const float* bg = (const float*)d_in[2];
  const float* W1 = (const float*)d_in[3];
  const float* b1 = (const float*)d_in[4];
  const float* Wa = (const float*)d_in[5];
  const float* ba = (const float*)d_in[6];
  const float* W2 = (const float*)d_in[7];
  const float* b2 = (const float*)d_in[8];
  float* out = (float*)d_out;
  (void)in_sizes; (void)n_in; (void)out_size; (void)ws_size;

  char* p = (char*)d_ws;
  auto take = [&](size_t bytes) { char* r = p; p += (bytes + 255) & ~(size_t)255; return r; };
  unsigned short* WaT = (unsigned short*)take((size_t)NE * HH * DD * 2);
  unsigned short* W1T = (unsigned short*)take((size_t)NE * HH * DD * 2);
  unsigned short* W2T = (unsigned short*)take((size_t)NE * DD * HH * 2);
  unsigned short* Xe  = (unsigned short*)take((size_t)ROWCAP * DD * 2);
  unsigned short* hb  = (unsigned short*)take((size_t)ROWCAP * HH * 2);
  float* contrib      = (float*)take((size_t)ROWCAP * DD * 4);
  int* counts   = (int*)take(64);
  int* offsets  = (int*)take(64);
  int* tok_e    = (int*)take(PAIRS * 4);
  int* tok_slot = (int*)take(PAIRS * 4);
  float* tok_w  = (float*)take(PAIRS * 4);
  int* pair_row = (int*)take(PAIRS * 4);
  float* rw     = (float*)take(ROWCAP * 4);
  int* tm_e     = (int*)take(TILE_CAP * 4);
  int* tm_row0  = (int*)take(TILE_CAP * 4);
  int* tm_nrow  = (int*)take(TILE_CAP * 4);
  int* ntp      = (int*)take(64);

  init_kernel<<<1, 64, 0, stream>>>(counts);
  transpose_kernel<<<NE * 16 * 64, 256, 0, stream>>>(Wa, WaT, DD, HH);
  transpose_kernel<<<NE * 16 * 64, 256, 0, stream>>>(W1, W1T, DD, HH);
  transpose_kernel<<<NE * 64 * 16, 256, 0, stream>>>(W2, W2T, HH, DD);
  gate_kernel<<<TOKENS, 256, 0, stream>>>(x, Wg, bg, counts, tok_e, tok_slot, tok_w);
  scan_kernel<<<1, 64, 0, stream>>>(counts, offsets, tm_e, tm_row0, tm_nrow, ntp);
  gather_kernel<<<PAIRS, 64, 0, stream>>>(x, tok_e, tok_slot, tok_w, offsets, Xe, pair_row, rw);
  gemm1_kernel<<<TILE_CAP * 32, 512, 64 * 1024, stream>>>(Xe, WaT, W1T, ba, b1, hb, tm_e, tm_row0, tm_nrow, ntp);
  gemm2_kernel<<<TILE_CAP * 8, 512, 48 * 1024, stream>>>(hb, W2T, b2, rw, contrib, tm_e, tm_row0, tm_nrow, ntp);
  combine_kernel<<<TOKENS, 256, 0, stream>>>(contrib, pair_row, out);
}

// Round 3
// 533.400 us; speedup vs baseline: 1.0992x; 1.0992x over previous
//
#include <hip/hip_runtime.h>
#include <hip/hip_bf16.h>
#include <math.h>

// Problem constants (B=4,S=1024,D=1024,H=4096,E=8,K=2)
#define TOKENS 4096
#define DD 1024
#define HH 4096
#define NE 8
#define PAIRS 8192     // TOKENS * K
#define ROWCAP 8448    // PAIRS + 256 slack for tile overread (BM=256)
#define TILE_CAP 40    // max sum ceil(n_e/256) = 39
#define G1_NT 16       // K-tiles (K=1024 / BK=64)
#define G2_NT 32       // K-tiles per K-split half (2048 / 64)

typedef __bf16 bf16x8 __attribute__((ext_vector_type(8)));
typedef float f32x4 __attribute__((ext_vector_type(4)));

__device__ __forceinline__ unsigned short f2bf(float f) {
  union { float f; unsigned int u; } c; c.f = f;
  unsigned int x = c.u;
  return (unsigned short)((x + 0x7fffu + ((x >> 16) & 1u)) >> 16);  // RNE
}

__device__ __forceinline__ void lds16(void* l, const void* g) {
  __builtin_amdgcn_global_load_lds((const __attribute__((address_space(1))) void*)g,
                                   (__attribute__((address_space(3))) void*)l, 16, 0, 0);
}

// ---------------- init ----------------
__global__ void init_kernel(int* counts) {
  if (threadIdx.x < NE) counts[threadIdx.x] = 0;
}

// ---------------- transpose+convert: [E][R][C] f32 -> [E][C][R] bf16 ----------------
__global__ __launch_bounds__(256) void transpose_kernel(const float* __restrict__ in,
                                                        unsigned short* __restrict__ out,
                                                        int R, int C) {
  int ntr = R >> 6, ntc = C >> 6;
  int per_e = ntr * ntc;
  int b = blockIdx.x;
  int e = b / per_e;
  int rem = b - e * per_e;
  int tr = rem / ntc, tc = rem - (rem / ntc) * ntc;
  const float* ie = in + (size_t)e * R * C;
  unsigned short* oe = out + (size_t)e * R * C;

  __shared__ float t[64][68];
  int tid = threadIdx.x;
  int lr = tid >> 2;
  int c4 = (tid & 3) << 4;
  const float* src = ie + (size_t)(tr * 64 + lr) * C + tc * 64 + c4;
  float4 v0 = *(const float4*)(src);
  float4 v1 = *(const float4*)(src + 4);
  float4 v2 = *(const float4*)(src + 8);
  float4 v3 = *(const float4*)(src + 12);
  *(float4*)&t[lr][c4] = v0;
  *(float4*)&t[lr][c4 + 4] = v1;
  *(float4*)&t[lr][c4 + 8] = v2;
  *(float4*)&t[lr][c4 + 12] = v3;
  __syncthreads();

  int oc = tid >> 2;
  int r0 = (tid & 3) << 4;
  unsigned int pk[8];
#pragma unroll
  for (int i = 0; i < 8; i++) {
    unsigned int lo = f2bf(t[r0 + 2 * i][oc]);
    unsigned int hi = f2bf(t[r0 + 2 * i + 1][oc]);
    pk[i] = lo | (hi << 16);
  }
  unsigned short* dst = oe + (size_t)(tc * 64 + oc) * R + tr * 64 + r0;
  *(uint4*)(dst) = make_uint4(pk[0], pk[1], pk[2], pk[3]);
  *(uint4*)(dst + 8) = make_uint4(pk[4], pk[5], pk[6], pk[7]);
}

// ---------------- gate ----------------
__global__ __launch_bounds__(256) void gate_kernel(const float* __restrict__ x,
    const float* __restrict__ Wg, const float* __restrict__ bg,
    int* __restrict__ counts, int* __restrict__ tok_e, int* __restrict__ tok_slot,
    float* __restrict__ tok_w) {
  int t = blockIdx.x, tid = threadIdx.x;
  const float* xr = x + (size_t)t * DD;
  float p[8] = {0, 0, 0, 0, 0, 0, 0, 0};
  for (int d = tid; d < DD; d += 256) {
    float xv = xr[d];
    const float4* wrow = (const float4*)(Wg + (size_t)d * NE);
    float4 w0 = wrow[0], w1 = wrow[1];
    p[0] += xv * w0.x; p[1] += xv * w0.y; p[2] += xv * w0.z; p[3] += xv * w0.w;
    p[4] += xv * w1.x; p[5] += xv * w1.y; p[6] += xv * w1.z; p[7] += xv * w1.w;
  }
#pragma unroll
  for (int e = 0; e < 8; e++) {
    p[e] += __shfl_down(p[e], 32);
    p[e] += __shfl_down(p[e], 16);
    p[e] += __shfl_down(p[e], 8);
    p[e] += __shfl_down(p[e], 4);
    p[e] += __shfl_down(p[e], 2);
    p[e] += __shfl_down(p[e], 1);
  }
  __shared__ float red[4][8];
  if ((tid & 63) == 0) {
#pragma unroll
    for (int e = 0; e < 8; e++) red[tid >> 6][e] = p[e];
  }
  __syncthreads();
  if (tid == 0) {
    float l[8];
#pragma unroll
    for (int e = 0; e < 8; e++) l[e] = red[0][e] + red[1][e] + red[2][e] + red[3][e] + bg[e];
    int e0 = 0; float l0 = l[0];
    for (int e = 1; e < 8; e++) if (l[e] > l0) { e0 = e; l0 = l[e]; }
    int e1 = -1; float l1 = -3.4e38f;
    for (int e = 0; e < 8; e++) if (e != e0 && l[e] > l1) { e1 = e; l1 = l[e]; }
    float w0 = 1.f / (1.f + __expf(l1 - l0));
    float w1 = 1.f - w0;
    int s0 = atomicAdd(&counts[e0], 1);
    int s1 = atomicAdd(&counts[e1], 1);
    tok_e[2 * t] = e0;     tok_slot[2 * t] = s0;     tok_w[2 * t] = w0;
    tok_e[2 * t + 1] = e1; tok_slot[2 * t + 1] = s1; tok_w[2 * t + 1] = w1;
  }
}

// ---------------- scan: expert offsets + 256-row tile map ----------------
__global__ void scan_kernel(const int* __restrict__ counts, int* __restrict__ offsets,
                            int* __restrict__ tm_e, int* __restrict__ tm_row0,
                            int* __restrict__ tm_nrow, int* __restrict__ ntp) {
  if (threadIdx.x != 0 || blockIdx.x != 0) return;
  int c[NE];
#pragma unroll
  for (int e = 0; e < NE; e++) c[e] = counts[e];
  int off = 0, nt = 0;
  for (int e = 0; e < NE; e++) {
    offsets[e] = off;
    for (int r = 0; r < c[e]; r += 256) {
      tm_e[nt] = e;
      tm_row0[nt] = off + r;
      tm_nrow[nt] = (c[e] - r < 256) ? (c[e] - r) : 256;
      nt++;
    }
    off += c[e];
  }
  *ntp = nt;
}

// ---------------- gather ----------------
__global__ __launch_bounds__(64) void gather_kernel(const float* __restrict__ x,
    const int* __restrict__ tok_e, const int* __restrict__ tok_slot,
    const float* __restrict__ tok_w, const int* __restrict__ offsets,
    unsigned short* __restrict__ Xe, int* __restrict__ pair_row, float* __restrict__ rw) {
  int pp = blockIdx.x, tid = threadIdx.x;
  int e = tok_e[pp];
  int row = offsets[e] + tok_slot[pp];
  int t = pp >> 1;
  const float* src = x + (size_t)t * DD + tid * 16;
  float4 v0 = *(const float4*)(src);
  float4 v1 = *(const float4*)(src + 4);
  float4 v2 = *(const float4*)(src + 8);
  float4 v3 = *(const float4*)(src + 12);
  unsigned int pk[8];
  pk[0] = f2bf(v0.x) | ((unsigned int)f2bf(v0.y) << 16);
  pk[1] = f2bf(v0.z) | ((unsigned int)f2bf(v0.w) << 16);
  pk[2] = f2bf(v1.x) | ((unsigned int)f2bf(v1.y) << 16);
  pk[3] = f2bf(v1.z) | ((unsigned int)f2bf(v1.w) << 16);
  pk[4] = f2bf(v2.x) | ((unsigned int)f2bf(v2.y) << 16);
  pk[5] = f2bf(v2.z) | ((unsigned int)f2bf(v2.w) << 16);
  pk[6] = f2bf(v3.x) | ((unsigned int)f2bf(v3.y) << 16);
  pk[7] = f2bf(v3.z) | ((unsigned int)f2bf(v3.w) << 16);
  unsigned short* dst = Xe + (size_t)row * DD + tid * 16;
  *(uint4*)(dst) = make_uint4(pk[0], pk[1], pk[2], pk[3]);
  *(uint4*)(dst + 8) = make_uint4(pk[4], pk[5], pk[6], pk[7]);
  if (tid == 0) { pair_row[pp] = row; rw[row] = tok_w[pp]; }
}

// ================= GEMM1: 8-phase-style schedule =================
// BM=256, BN=128 dual (Wa,W1), BK=64, 512 thr (8 waves 2Mx4N), 128KB LDS.
// Per K-tile: 4 phases x 16 MFMA; 1 half-tile staged/phase; vmcnt(6) once/K-tile.
// T2 swizzle: chunk16 ^= (row&7), pre-swizzled global src + swizzled ds_read.
__global__ __launch_bounds__(512, 2) void gemm1_kernel(
    const unsigned short* __restrict__ Xe,
    const unsigned short* __restrict__ WaT,   // [E][H][D] bf16
    const unsigned short* __restrict__ W1T,
    const float* __restrict__ ba, const float* __restrict__ b1,
    unsigned short* __restrict__ h,
    const int* __restrict__ tm_e, const int* __restrict__ tm_row0,
    const int* __restrict__ tm_nrow, const int* __restrict__ ntp) {
  __shared__ unsigned short sm[8][8192];  // [buf*4 + slot]; slot 0=A0,1=A1,2=Wa,3=W1

  int work = blockIdx.x;
  int tile = work >> 5;
  if (tile >= *ntp) return;
  int n0 = (work & 31) << 7;
  int e = tm_e[tile], row0 = tm_row0[tile], nrow = tm_nrow[tile];

  int tid = threadIdx.x;
  int lane = tid & 63, wid = tid >> 6;
  int wm = wid >> 2, wn = wid & 3;     // 2M x 4N
  int fr = lane & 15, kc = lane >> 4;

  const unsigned short* gA  = Xe + (size_t)row0 * DD;
  const unsigned short* gA1 = gA + (size_t)128 * DD;
  const unsigned short* gBa = WaT + ((size_t)e << 22) + (size_t)n0 * DD;
  const unsigned short* gBu = W1T + ((size_t)e << 22) + (size_t)n0 * DD;

  int srow = tid >> 3;                         // 0..63 (second load: +64)
  int sx0 = (((tid & 7) ^ (srow & 7)) << 3);   // swizzled source chunk offset (elements)

  // stage one 128x64 half-tile (2 loads/thread)
  auto stg = [&](int tt, int slot, const unsigned short* gsrc) {
    int c = tt < G1_NT ? tt : G1_NT - 1;
    unsigned short* L = &sm[((tt & 1) << 2) | slot][0];
    const unsigned short* s = gsrc + (size_t)srow * DD + (c << 6) + sx0;
    lds16(L + (size_t)tid * 8, s);
    lds16(L + (size_t)(tid + 512) * 8, s + (size_t)64 * DD);
  };
  // swizzled fragment read
  auto fragp = [&](int buf, int slot, int r, int ks) {
    return (const bf16x8*)(&sm[(buf << 2) | slot][0] + r * 64 +
                           ((((ks << 2) | kc) ^ (r & 7)) << 3));
  };

  f32x4 accA[8][2], accU[8][2];
  f32x4 z = {0.f, 0.f, 0.f, 0.f};
#pragma unroll
  for (int m = 0; m < 8; m++)
#pragma unroll
    for (int n = 0; n < 2; n++) { accA[m][n] = z; accU[m][n] = z; }

  // prologue: T0.h2,h3,h0,h1, T1.h2,h3,h0 (order matters for vmcnt counting)
  stg(0, 2, gBa); stg(0, 3, gBu); stg(0, 0, gA); stg(0, 1, gA1);
  stg(1, 2, gBa); stg(1, 3, gBu); stg(1, 0, gA);
  asm volatile("s_waitcnt vmcnt(6)\ns_barrier" ::: "memory");

  for (int T = 0; T < G1_NT; ++T) {
    int buf = T & 1;
    bf16x8 a[4][2], bA[2][2], bU[2][2];
    // ---- q1: a(mh0)+bA reads; stage (T+1).h1; MFMA (mh0, A) ----
#pragma unroll
    for (int m = 0; m < 4; m++)
#pragma unroll
      for (int ks = 0; ks < 2; ks++) {
        int R = wm * 128 + m * 16 + fr;
        a[m][ks] = *fragp(buf, R >> 7, R & 127, ks);
      }
#pragma unroll
    for (int n = 0; n < 2; n++)
#pragma unroll
      for (int ks = 0; ks < 2; ks++)
        bA[n][ks] = *fragp(buf, 2, wn * 32 + n * 16 + fr, ks);
    stg(T + 1, 1, gA1);
    __builtin_amdgcn_s_setprio(1);
#pragma unroll
    for (int m = 0; m < 4; m++)
#pragma unroll
      for (int n = 0; n < 2; n++)
#pragma unroll
        for (int ks = 0; ks < 2; ks++)
          accA[m][n] = __builtin_amdgcn_mfma_f32_16x16x32_bf16(a[m][ks], bA[n][ks], accA[m][n], 0, 0, 0);
    __builtin_amdgcn_s_setprio(0);
    asm volatile("s_waitcnt lgkmcnt(0)\ns_barrier" ::: "memory");
    // ---- q2: bU reads; stage (T+2).h2; MFMA (mh0, U) ----
#pragma unroll
    for (int n = 0; n < 2; n++)
#pragma unroll
      for (int ks = 0; ks < 2; ks++)
        bU[n][ks] = *fragp(buf, 3, wn * 32 + n * 16 + fr, ks);
    stg(T + 2, 2, gBa);
    __builtin_amdgcn_s_setprio(1);
#pragma unroll
    for (int m = 0; m < 4; m++)
#pragma unroll
      for (int n = 0; n < 2; n++)
#pragma unroll
        for (int ks = 0; ks < 2; ks++)
          accU[m][n] = __builtin_amdgcn_mfma_f32_16x16x32_bf16(a[m][ks], bU[n][ks], accU[m][n], 0, 0, 0);
    __builtin_amdgcn_s_setprio(0);
    asm volatile("s_waitcnt lgkmcnt(0)\ns_barrier" ::: "memory");
    // ---- q3: a(mh1) reads; stage (T+2).h3; MFMA (mh1, A) ----
#pragma unroll
    for (int m = 0; m < 4; m++)
#pragma unroll
      for (int ks = 0; ks < 2; ks++) {
        int R = wm * 128 + 64 + m * 16 + fr;
        a[m][ks] = *fragp(buf, R >> 7, R & 127, ks);
      }
    stg(T + 2, 3, gBu);
    __builtin_amdgcn_s_setprio(1);
#pragma unroll
    for (int m = 0; m < 4; m++)
#pragma unroll
      for (int n = 0; n < 2; n++)
#pragma unroll
        for (int ks = 0; ks < 2; ks++)
          accA[4 + m][n] = __builtin_amdgcn_mfma_f32_16x16x32_bf16(a[m][ks], bA[n][ks], accA[4 + m][n], 0, 0, 0);
    __builtin_amdgcn_s_setprio(0);
    asm volatile("s_waitcnt lgkmcnt(0)\ns_barrier" ::: "memory");
    // ---- q4: stage (T+2).h0; MFMA (mh1, U); vmcnt(6) certifies next K-tile ----
    stg(T + 2, 0, gA);
    __builtin_amdgcn_s_setprio(1);
#pragma unroll
    for (int m = 0; m < 4; m++)
#pragma unroll
      for (int n = 0; n < 2; n++)
#pragma unroll
        for (int ks = 0; ks < 2; ks++)
          accU[4 + m][n] = __builtin_amdgcn_mfma_f32_16x16x32_bf16(a[m][ks], bU[n][ks], accU[4 + m][n], 0, 0, 0);
    __builtin_amdgcn_s_setprio(0);
    asm volatile("s_waitcnt vmcnt(6)\ns_barrier" ::: "memory");
  }

  // epilogue: SwiGLU -> bf16 h
  int lr4 = kc * 4;
#pragma unroll
  for (int n = 0; n < 2; n++) {
    int col = n0 + wn * 32 + n * 16 + fr;
    float bav = ba[e * HH + col];
    float buv = b1[e * HH + col];
#pragma unroll
    for (int m = 0; m < 8; m++) {
#pragma unroll
      for (int j = 0; j < 4; j++) {
        int r = wm * 128 + m * 16 + lr4 + j;
        if (r < nrow) {
          float av = accA[m][n][j] + bav;
          float uv = accU[m][n][j] + buv;
          float s = __builtin_amdgcn_rcpf(1.f + __expf(-av));
          h[(size_t)(row0 + r) * HH + col] = f2bf(av * s * uv);
        }
      }
    }
  }
}

// ================= GEMM2: 2-phase/K-tile counted schedule, K-split=2 =================
// BM=256, BN=128, BK=64, 512 thr (8 waves 2Mx4N). A x3 bufs, B x3 bufs (144KB LDS).
__global__ __launch_bounds__(512, 2) void gemm2_kernel(
    const unsigned short* __restrict__ hb,
    const unsigned short* __restrict__ W2T,   // [E][D][H] bf16
    const float* __restrict__ b2, const float* __restrict__ rw,
    float* __restrict__ contribA, float* __restrict__ contribB,
    const int* __restrict__ tm_e, const int* __restrict__ tm_row0,
    const int* __restrict__ tm_nrow, const int* __restrict__ ntp) {
  __shared__ unsigned short sm[9][8192];  // slots 0..5: A (bufs x 2 halves), 6..8: B bufs

  int work = blockIdx.x;
  int tile = work >> 4;
  if (tile >= *ntp) return;
  int rem = work & 15;
  int n0 = (rem >> 1) << 7;
  int kh = rem & 1;
  int e = tm_e[tile], row0 = tm_row0[tile], nrow = tm_nrow[tile];

  int tid = threadIdx.x;
  int lane = tid & 63, wid = tid >> 6;
  int wm = wid >> 2, wn = wid & 3;     // 2M x 4N
  int fr = lane & 15, kc = lane >> 4;

  const unsigned short* gA = hb + (size_t)row0 * HH + kh * 2048;
  const unsigned short* gB = W2T + ((size_t)e << 22) + (size_t)n0 * HH + kh * 2048;

  int srow = tid >> 3;
  int sx0 = (((tid & 7) ^ (srow & 7)) << 3);

  auto stgA = [&](int tt) {   // both A halves, 4 loads
    int c = tt < G2_NT ? tt : G2_NT - 1;
    int sl = (tt % 3) << 1;
    const unsigned short* s = gA + (size_t)srow * HH + (c << 6) + sx0;
    lds16(&sm[sl][0] + (size_t)tid * 8, s);
    lds16(&sm[sl][0] + (size_t)(tid + 512) * 8, s + (size_t)64 * HH);
    lds16(&sm[sl + 1][0] + (size_t)tid * 8, s + (size_t)128 * HH);
    lds16(&sm[sl + 1][0] + (size_t)(tid + 512) * 8, s + (size_t)192 * HH);
  };
  auto stgB = [&](int tt) {   // one B half-tile, 2 loads
    int c = tt < G2_NT ? tt : G2_NT - 1;
    unsigned short* L = &sm[6 + tt % 3][0];
    const unsigned short* s = gB + (size_t)srow * HH + (c << 6) + sx0;
    lds16(L + (size_t)tid * 8, s);
    lds16(L + (size_t)(tid + 512) * 8, s + (size_t)64 * HH);
  };
  auto fragp = [&](int slot, int r, int ks) {
    return (const bf16x8*)(&sm[slot][0] + r * 64 + ((((ks << 2) | kc) ^ (r & 7)) << 3));
  };

  f32x4 acc[8][2];
  f32x4 z = {0.f, 0.f, 0.f, 0.f};
#pragma unroll
  for (int m = 0; m < 8; m++)
#pragma unroll
    for (int n = 0; n < 2; n++) acc[m][n] = z;

  // prologue: T0.B, T0.A, T1.B, T1.A, T2.B (14 loads); certify T0
  stgB(0); stgA(0); stgB(1); stgA(1); stgB(2);
  asm volatile("s_waitcnt vmcnt(6)\ns_barrier" ::: "memory");

  for (int T = 0; T < G2_NT; ++T) {
    int slA = (T % 3) << 1;
    int slB = 6 + T % 3;
    bf16x8 a[4][2], b[2][2];
    // ---- q1 (mh0): reads a+b; stage (T+2).A; MFMA ----
#pragma unroll
    for (int m = 0; m < 4; m++)
#pragma unroll
      for (int ks = 0; ks < 2; ks++) {
        int R = wm * 128 + m * 16 + fr;
        a[m][ks] = *fragp(slA + (R >> 7), R & 127, ks);
      }
#pragma unroll
    for (int n = 0; n < 2; n++)
#pragma unroll
      for (int ks = 0; ks < 2; ks++)
        b[n][ks] = *fragp(slB, wn * 32 + n * 16 + fr, ks);
    stgA(T + 2);
    __builtin_amdgcn_s_setprio(1);
#pragma unroll
    for (int m = 0; m < 4; m++)
#pragma unroll
      for (int n = 0; n < 2; n++)
#pragma unroll
        for (int ks = 0; ks < 2; ks++)
          acc[m][n] = __builtin_amdgcn_mfma_f32_16x16x32_bf16(a[m][ks], b[n][ks], acc[m][n], 0, 0, 0);
    __builtin_amdgcn_s_setprio(0);
    asm volatile("s_waitcnt lgkmcnt(0)\ns_barrier" ::: "memory");
    // ---- q2 (mh1): reads a; stage (T+3).B; MFMA; certify T+1 ----
#pragma unroll
    for (int m = 0; m < 4; m++)
#pragma unroll
      for (int ks = 0; ks < 2; ks++) {
        int R = wm * 128 + 64 + m * 16 + fr;
        a[m][ks] = *fragp(slA + (R >> 7), R & 127, ks);
      }
    stgB(T + 3);
    __builtin_amdgcn_s_setprio(1);
#pragma unroll
    for (int m = 0; m < 4; m++)
#pragma unroll
      for (int n = 0; n < 2; n++)
#pragma unroll
        for (int ks = 0; ks < 2; ks++)
          acc[4 + m][n] = __builtin_amdgcn_mfma_f32_16x16x32_bf16(a[m][ks], b[n][ks], acc[4 + m][n], 0, 0, 0);
    __builtin_amdgcn_s_setprio(0);
    asm volatile("s_waitcnt vmcnt(6) lgkmcnt(0)\ns_barrier" ::: "memory");
  }

  float b2v[2];
#pragma unroll
  for (int n = 0; n < 2; n++)
    b2v[n] = (kh == 0) ? b2[e * DD + n0 + wn * 32 + n * 16 + fr] : 0.f;
  float* cbuf = kh ? contribB : contribA;
  int lr4 = kc * 4;
#pragma unroll
  for (int m = 0; m < 8; m++) {
#pragma unroll
    for (int j = 0; j < 4; j++) {
      int r = wm * 128 + m * 16 + lr4 + j;
      if (r < nrow) {
        float wv = rw[row0 + r];
        float* dst = cbuf + (size_t)(row0 + r) * DD + n0 + wn * 32 + fr;
        dst[0]  = wv * (acc[m][0][j] + b2v[0]);
        dst[16] = wv * (acc[m][1][j] + b2v[1]);
      }
    }
  }
}

// ---------------- combine: out[t] = sum of 2 pairs x 2 K-halves ----------------
__global__ __launch_bounds__(256) void combine_kernel(const float* __restrict__ cA,
    const float* __restrict__ cB, const int* __restrict__ pair_row,
    float* __restrict__ out) {
  int t = blockIdx.x, tid = threadIdx.x;
  int r0 = pair_row[2 * t], r1 = pair_row[2 * t + 1];
  const float4* a0 = (const float4*)(cA + (size_t)r0 * DD);
  const float4* b0 = (const float4*)(cB + (size_t)r0 * DD);
  const float4* a1 = (const float4*)(cA + (size_t)r1 * DD);
  const float4* b1 = (const float4*)(cB + (size_t)r1 * DD);
  float4* o = (float4*)(out + (size_t)t * DD);
  float4 x0 = a0[tid], y0 = b0[tid], x1 = a1[tid], y1 = b1[tid];
  o[tid] = make_float4((x0.x + y0.x) + (x1.x + y1.x),
                       (x0.y + y0.y) + (x1.y + y1.y),
                       (x0.z + y0.z) + (x1.z + y1.z),
                       (x0.w + y0.w) + (x1.w + y1.w));
}

extern "C" void kernel_launch(void* const* d_in, const int* in_sizes, int n_in,
                              void* d_out, int out_size, void* d_ws, size_t ws_size,
                              hipStream_t stream) {
  const float* x  = (const float*)d_in[0];
  const float* Wg = (const float*)d_in[1];
  const float* bg = (const float*)d_in[2];
  const float* W1 = (const float*)d_in[3];
  const float* b1 = (const float*)d_in[4];
  const float* Wa = (const float*)d_in[5];
  const float* ba = (const float*)d_in[6];
  const float* W2 = (const float*)d_in[7];
  const float* b2 = (const float*)d_in[8];
  float* out = (float*)d_out;
  (void)in_sizes; (void)n_in; (void)out_size; (void)ws_size;

  char* p = (char*)d_ws;
  auto take = [&](size_t bytes) { char* r = p; p += (bytes + 255) & ~(size_t)255; return r; };
  unsigned short* WaT = (unsigned short*)take((size_t)NE * HH * DD * 2);
  unsigned short* W1T = (unsigned short*)take((size_t)NE * HH * DD * 2);
  unsigned short* W2T = (unsigned short*)take((size_t)NE * DD * HH * 2);
  unsigned short* Xe  = (unsigned short*)take((size_t)ROWCAP * DD * 2);
  unsigned short* hb  = (unsigned short*)take((size_t)ROWCAP * HH * 2);
  float* contribA     = (float*)take((size_t)ROWCAP * DD * 4);
  int* counts   = (int*)take(64);
  int* offsets  = (int*)take(64);
  int* tok_e    = (int*)take(PAIRS * 4);
  int* tok_slot = (int*)take(PAIRS * 4);
  float* tok_w  = (float*)take(PAIRS * 4);
  int* pair_row = (int*)take(PAIRS * 4);
  float* rw     = (float*)take(ROWCAP * 4);
  int* tm_e     = (int*)take(TILE_CAP * 4);
  int* tm_row0  = (int*)take(TILE_CAP * 4);
  int* tm_nrow  = (int*)take(TILE_CAP * 4);
  int* ntp      = (int*)take(64);
  // contribB aliases WaT (dead after gemm1; gemm2 runs strictly after on the stream)
  float* contribB = (float*)WaT;

  init_kernel<<<1, 64, 0, stream>>>(counts);
  transpose_kernel<<<NE * 16 * 64, 256, 0, stream>>>(Wa, WaT, DD, HH);
  transpose_kernel<<<NE * 16 * 64, 256, 0, stream>>>(W1, W1T, DD, HH);
  transpose_kernel<<<NE * 64 * 16, 256, 0, stream>>>(W2, W2T, HH, DD);
  gate_kernel<<<TOKENS, 256, 0, stream>>>(x, Wg, bg, counts, tok_e, tok_slot, tok_w);
  scan_kernel<<<1, 64, 0, stream>>>(counts, offsets, tm_e, tm_row0, tm_nrow, ntp);
  gather_kernel<<<PAIRS, 64, 0, stream>>>(x, tok_e, tok_slot, tok_w, offsets, Xe, pair_row, rw);
  gemm1_kernel<<<TILE_CAP * 32, 512, 0, stream>>>(Xe, WaT, W1T, ba, b1, hb, tm_e, tm_row0, tm_nrow, ntp);
  gemm2_kernel<<<TILE_CAP * 16, 512, 0, stream>>>(hb, W2T, b2, rw, contribA, contribB, tm_e, tm_row0, tm_nrow, ntp);
  combine_kernel<<<TOKENS, 256, 0, stream>>>(contribA, contribB, pair_row, out);
}